// Round 4
// baseline (252.380 us; speedup 1.0000x reference)
//
#include <hip/hip_runtime.h>

#define AA2AU   1.8897261258369282f
#define AU2KCAL 627.5094740630558f

__global__ void zero_out_kernel(float* __restrict__ out, int n) {
    int i = blockIdx.x * blockDim.x + threadIdx.x;
    if (i < n) out[i] = 0.0f;
}

__global__ __launch_bounds__(256) void RepulsionEnergy_18562848654089_kernel(
    const float* __restrict__ pos,
    const float* __restrict__ arep,
    const float* __restrict__ zeff,
    const int*   __restrict__ z,
    const int*   __restrict__ ei,
    const int*   __restrict__ batch,
    float*       __restrict__ out,
    int E)
{
    int e = blockIdx.x * blockDim.x + threadIdx.x;
    if (e >= E) return;

    int s = ei[e];
    int t = ei[E + e];
    int bs = batch[s];
    int bt = batch[t];
    if (bs != bt) return;

    float dx = pos[3 * s + 0] - pos[3 * t + 0];
    float dy = pos[3 * s + 1] - pos[3 * t + 1];
    float dz = pos[3 * s + 2] - pos[3 * t + 2];
    float d2 = dx * dx + dy * dy + dz * dz;
    if (d2 > 9.0f) return;                       // CUTOFF = 3.0 Angstrom

    float d = fmaxf(sqrtf(d2), 1e-9f);
    float d_au = d * AA2AU;
    int zs = z[s], zt = z[t];
    float a = sqrtf(arep[zs] * arep[zt]);
    float ex = __expf(-a * d_au * sqrtf(d_au));  // d_au^1.5 = d_au*sqrt(d_au)
    float rep = zeff[zs] * zeff[zt] * ex / d_au;
    atomicAdd(&out[bs], rep * AU2KCAL);
}

extern "C" void kernel_launch(void* const* d_in, const int* in_sizes, int n_in,
                              void* d_out, int out_size, void* d_ws, size_t ws_size,
                              hipStream_t stream) {
    const float* pos   = (const float*)d_in[0];
    const float* arep  = (const float*)d_in[1];
    const float* zeff  = (const float*)d_in[2];
    const int*   z     = (const int*)d_in[3];
    const int*   ei    = (const int*)d_in[4];
    const int*   batch = (const int*)d_in[5];
    float* out = (float*)d_out;

    const int E = in_sizes[4] / 2;

    zero_out_kernel<<<(out_size + 255) / 256, 256, 0, stream>>>(out, out_size);

    const int threads = 256;
    const int blocks  = (E + threads - 1) / threads;   // one thread per edge
    RepulsionEnergy_18562848654089_kernel<<<blocks, threads, 0, stream>>>(
        pos, arep, zeff, z, ei, batch, out, E);
}